// Round 1
// baseline (5307.425 us; speedup 1.0000x reference)
//
#include <hip/hip_runtime.h>
#include <hip/hip_bf16.h>
#include <math.h>

#define T_TOK 8192
#define NH 16
#define HD 128
#define CH3 6144   // 3*NH*HD
#define CH1 2048   // NH*HD

// ---------------------------------------------------------------------------
// Kernel 1: preprocessing (conv+silu, l2norm, gates). One wave per (t, h).
// Each lane handles dims d = lane and lane+64.
// ---------------------------------------------------------------------------
__global__ __launch_bounds__(64)
void kda_prep(const float* __restrict__ mixed, const float* __restrict__ fg,
              const float* __restrict__ beta, const float* __restrict__ cw,
              const float* __restrict__ dtb, const float* __restrict__ alog,
              float* __restrict__ qp, float* __restrict__ kp, float* __restrict__ vp,
              float* __restrict__ dp, float* __restrict__ bp) {
  const int t = blockIdx.x;
  const int h = blockIdx.y;
  const int lane = threadIdx.x;  // 0..63

  float vals[3][2];
#pragma unroll
  for (int s = 0; s < 3; ++s) {
#pragma unroll
    for (int e = 0; e < 2; ++e) {
      const int d = lane + e * 64;
      const int c = s * CH1 + h * HD + d;
      const float4 w = ((const float4*)cw)[c];
      const float wv[4] = {w.x, w.y, w.z, w.w};
      float acc = 0.f;
#pragma unroll
      for (int j = 0; j < 4; ++j) {
        const int tt = t - 3 + j;
        if (tt >= 0) acc += mixed[(size_t)tt * CH3 + c] * wv[j];
      }
      // SiLU
      acc = acc / (1.f + expf(-acc));
      vals[s][e] = acc;
    }
  }
  // l2norm over the 128 dims for q (s=0, with D^-0.5 scale) and k (s=1)
#pragma unroll
  for (int s = 0; s < 2; ++s) {
    float ss = vals[s][0] * vals[s][0] + vals[s][1] * vals[s][1];
    ss += __shfl_xor(ss, 1);  ss += __shfl_xor(ss, 2);  ss += __shfl_xor(ss, 4);
    ss += __shfl_xor(ss, 8);  ss += __shfl_xor(ss, 16); ss += __shfl_xor(ss, 32);
    float inv = 1.f / sqrtf(ss + 1e-6f);
    if (s == 0) inv *= 0.08838834764831845f;  // 128^-0.5
    vals[s][0] *= inv;
    vals[s][1] *= inv;
  }
  // decay = exp(-exp(alog[h]) * softplus(fg + dt_bias))
  const float ea = expf(alog[h]);
  float dec[2];
#pragma unroll
  for (int e = 0; e < 2; ++e) {
    const int d = lane + e * 64;
    const float x = fg[(size_t)t * CH1 + h * HD + d] + dtb[h * HD + d];
    const float sp = (x > 20.f) ? x : log1pf(expf(x));
    dec[e] = expf(-ea * sp);
  }
  const size_t ob = ((size_t)t * NH + h) * HD + lane;
  qp[ob] = vals[0][0]; qp[ob + 64] = vals[0][1];
  kp[ob] = vals[1][0]; kp[ob + 64] = vals[1][1];
  vp[ob] = vals[2][0]; vp[ob + 64] = vals[2][1];
  dp[ob] = dec[0];     dp[ob + 64] = dec[1];
  if (lane == 0) bp[t * NH + h] = 1.f / (1.f + expf(-beta[t * NH + h]));
}

// ---------------------------------------------------------------------------
// Kernel 2: recurrent scan. State columns S[:, v] are independent.
// Grid: 16 heads x 8 v-groups (16 cols each). Block 256 = 4 waves.
// Per column: 16 lanes, each lane holds 8 state elements (k-slice).
// Reductions over the 16 klanes via __shfl_xor butterflies (in-wave).
// Global loads double-buffered in registers.
// ---------------------------------------------------------------------------
__global__ __launch_bounds__(256)
void kda_scan(const float* __restrict__ qp, const float* __restrict__ kp,
              const float* __restrict__ vp, const float* __restrict__ dp,
              const float* __restrict__ bp, float* __restrict__ out) {
  const int h  = blockIdx.x >> 3;
  const int vg = blockIdx.x & 7;
  const int lane  = threadIdx.x & 63;
  const int wave  = threadIdx.x >> 6;
  const int klane = lane & 15;
  const int col   = (wave << 2) | (lane >> 4);  // 0..15
  const int vcol  = (vg << 4) + col;            // 0..127
  const int kb    = klane << 3;                 // 0..120

  const size_t rowoff_k = (size_t)h * HD + kb;
  const size_t rowoff_v = (size_t)h * HD + vcol;

  float S0 = 0.f, S1 = 0.f, S2 = 0.f, S3 = 0.f, S4 = 0.f, S5 = 0.f, S6 = 0.f, S7 = 0.f;

  float4 Ka0, Ka1, Da0, Da1, Qa0, Qa1; float Va, Ba;
  float4 Kb0, Kb1, Db0, Db1, Qb0, Qb1; float Vb, Bb;

#define LOADROW(t, K0, K1, D0, D1, Q0, Q1, VV, BB) do {                         \
    const size_t r = (size_t)(t) * CH1 + rowoff_k;                              \
    K0 = *(const float4*)(kp + r); K1 = *(const float4*)(kp + r + 4);           \
    D0 = *(const float4*)(dp + r); D1 = *(const float4*)(dp + r + 4);           \
    Q0 = *(const float4*)(qp + r); Q1 = *(const float4*)(qp + r + 4);           \
    VV = vp[(size_t)(t) * CH1 + rowoff_v];                                      \
    BB = bp[(t) * NH + h];                                                      \
  } while (0)

#define DOSTEP(tt, K0, K1, D0, D1, Q0, Q1, VV, BB) do {                         \
    S0 *= D0.x; S1 *= D0.y; S2 *= D0.z; S3 *= D0.w;                             \
    S4 *= D1.x; S5 *= D1.y; S6 *= D1.z; S7 *= D1.w;                             \
    float p = S0 * K0.x + S1 * K0.y + S2 * K0.z + S3 * K0.w                     \
            + S4 * K1.x + S5 * K1.y + S6 * K1.z + S7 * K1.w;                    \
    p += __shfl_xor(p, 1); p += __shfl_xor(p, 2);                               \
    p += __shfl_xor(p, 4); p += __shfl_xor(p, 8);                               \
    const float dl = BB * (VV - p);                                             \
    S0 += K0.x * dl; S1 += K0.y * dl; S2 += K0.z * dl; S3 += K0.w * dl;         \
    S4 += K1.x * dl; S5 += K1.y * dl; S6 += K1.z * dl; S7 += K1.w * dl;         \
    float oo = S0 * Q0.x + S1 * Q0.y + S2 * Q0.z + S3 * Q0.w                    \
             + S4 * Q1.x + S5 * Q1.y + S6 * Q1.z + S7 * Q1.w;                   \
    oo += __shfl_xor(oo, 1); oo += __shfl_xor(oo, 2);                           \
    oo += __shfl_xor(oo, 4); oo += __shfl_xor(oo, 8);                           \
    if (klane == 0) out[(size_t)(tt) * CH1 + rowoff_v] = oo;                    \
  } while (0)

  LOADROW(0, Ka0, Ka1, Da0, Da1, Qa0, Qa1, Va, Ba);
  for (int t = 0; t < T_TOK; t += 2) {
    LOADROW(t + 1, Kb0, Kb1, Db0, Db1, Qb0, Qb1, Vb, Bb);
    DOSTEP(t, Ka0, Ka1, Da0, Da1, Qa0, Qa1, Va, Ba);
    if (t + 2 < T_TOK) LOADROW(t + 2, Ka0, Ka1, Da0, Da1, Qa0, Qa1, Va, Ba);
    DOSTEP(t + 1, Kb0, Kb1, Db0, Db1, Qb0, Qb1, Vb, Bb);
  }
#undef LOADROW
#undef DOSTEP
}

// ---------------------------------------------------------------------------
extern "C" void kernel_launch(void* const* d_in, const int* in_sizes, int n_in,
                              void* d_out, int out_size, void* d_ws, size_t ws_size,
                              hipStream_t stream) {
  const float* mixed = (const float*)d_in[0];
  const float* fg    = (const float*)d_in[1];
  const float* beta  = (const float*)d_in[2];
  const float* cw    = (const float*)d_in[3];
  const float* dtb   = (const float*)d_in[4];
  const float* alog  = (const float*)d_in[5];
  float* out = (float*)d_out;

  const size_t n1 = (size_t)T_TOK * CH1;  // 16.8M elements per tensor
  float* qp = (float*)d_ws;
  float* kp = qp + n1;
  float* vp = kp + n1;
  float* dp = vp + n1;
  float* bp = dp + n1;

  dim3 g1(T_TOK, NH), b1(64);
  hipLaunchKernelGGL(kda_prep, g1, b1, 0, stream, mixed, fg, beta, cw, dtb, alog,
                     qp, kp, vp, dp, bp);
  hipLaunchKernelGGL(kda_scan, dim3(NH * 8), dim3(256), 0, stream,
                     qp, kp, vp, dp, bp, out);
  (void)in_sizes; (void)n_in; (void)out_size; (void)ws_size;
}

// Round 2
// 2555.528 us; speedup vs baseline: 2.0768x; 2.0768x over previous
//
#include <hip/hip_runtime.h>
#include <math.h>

#define NH 16
#define HD 128
#define CH1 2048
#define CH3 6144
#define CK 64
#define NC 128
#define PCH 132   // LDS pitch for 64x128 tensors (bank-friendly, 16B-aligned rows)
#define MP 68     // LDS pitch for 64x64 M / N^T

// workspace layout (float offsets)
#define QT_OFF  0u            // tiled q~   [2048 ch][8g][64t][16d]
#define KBT_OFF 16777216u     // kbar^T     [2048 ch][128k][64t]
#define U0_OFF  33554432u     // U0 natural [8192 t][16 h][128 d]
#define Z_OFF   50331648u     // tiled Z    [2048 ch][8g][64t][16d]
#define W_OFF   67108864u     // tiled W    [2048 ch][8g][64t][8s]
#define ECG_OFF 75497472u     // e^{cg63}   [2048 ch][128 k]
#define SLAB_OFF 75759616u    // per-K3-block: S[128][8] + Un[64][8] + Ut[8][64]

// ---------------------------------------------------------------------------
// Kernel A: per-(chunk, head) fully parallel. conv+silu+l2norm+gates, then
// A/W pair-matrices (per-pair exponents, always <=0), (I+B A)^-1, Z, U0.
// ---------------------------------------------------------------------------
__global__ __launch_bounds__(512, 2)
void kda_chunk(const float* __restrict__ mixed, const float* __restrict__ fg,
               const float* __restrict__ beta, const float* __restrict__ cw,
               const float* __restrict__ dtb, const float* __restrict__ alog,
               float* __restrict__ qt_g, float* __restrict__ kbt_g,
               float* __restrict__ u0_g, float* __restrict__ z_g,
               float* __restrict__ w_g, float* __restrict__ ecg_g) {
  __shared__ float lds[35520];
  float* kL  = lds;            // [64][132]
  float* qL  = lds + 8448;     // [64][132], later RHS
  float* cgL = lds + 16896;    // [64][132]
  float* ML  = lds + 25344;    // [64][68]
  float* NT  = lds + 29696;    // [64][68]  (N transposed: NT[col][row])
  float* GB  = lds + 34048;    // [768]
  float* bL  = lds + 34816;    // [64]
  float* nrm = lds + 34880;    // [640]

  const int tid = threadIdx.x;
  const int bid = blockIdx.x;
  const int c = bid >> 4, h = bid & 15;
  const int t0 = c * CK;
  const float ea = __expf(alog[h]);

  // W zero-fill (store-before-barrier ordering makes later overwrites safe)
  {
    size_t wb = (size_t)bid * 4096;
#pragma unroll
    for (int i = 0; i < 8; ++i) w_g[wb + tid + 512 * i] = 0.f;
  }

  // (a) g = -exp(alog)*softplus(fg+dtb) -> cgL
  for (int it = 0; it < 16; ++it) {
    int cell = tid + (it << 9);
    int d = cell & 127, t = cell >> 7;
    float x = fg[(size_t)(t0 + t) * CH1 + h * HD + d] + dtb[h * HD + d];
    float sp = (x > 20.f) ? x : log1pf(__expf(x));
    cgL[t * PCH + d] = -ea * sp;
  }
  if (tid < 64) bL[tid] = 1.f / (1.f + __expf(-beta[(size_t)(t0 + tid) * NH + h]));
  __syncthreads();

  // inclusive prefix over t (per dim) + ecg writeout
  if (tid < 128) {
    float a = 0.f;
    for (int t = 0; t < 64; ++t) { a += cgL[t * PCH + tid]; cgL[t * PCH + tid] = a; }
    ecg_g[(size_t)bid * 128 + tid] = __expf(a);
  }

  // (b) conv+silu for q (sec0) and k (sec1)
  for (int it = 0; it < 32; ++it) {
    int cell = tid + (it << 9);
    int d = cell & 127, sec = (cell >> 7) & 1, t = cell >> 8;
    int ch = sec * CH1 + h * HD + d;
    float4 w4 = ((const float4*)cw)[ch];
    int rbase = t0 + t - 3;
    float acc;
    if (rbase >= 0) {
      const float* mp = mixed + (size_t)rbase * CH3 + ch;
      acc = mp[0] * w4.x + mp[CH3] * w4.y + mp[2 * CH3] * w4.z + mp[3 * CH3] * w4.w;
    } else {
      acc = 0.f;
      if (rbase + 0 >= 0) acc += mixed[(size_t)(rbase + 0) * CH3 + ch] * w4.x;
      if (rbase + 1 >= 0) acc += mixed[(size_t)(rbase + 1) * CH3 + ch] * w4.y;
      if (rbase + 2 >= 0) acc += mixed[(size_t)(rbase + 2) * CH3 + ch] * w4.z;
      acc += mixed[(size_t)(rbase + 3) * CH3 + ch] * w4.w;
    }
    acc = acc / (1.f + __expf(-acc));
    float* dst = (sec == 0) ? qL : kL;
    dst[t * PCH + d] = acc;
  }
  __syncthreads();

  // l2norm partials
  {
    int sec = tid >> 8, t = (tid >> 2) & 63, r = tid & 3;
    const float* src = (sec == 0) ? qL : kL;
    float s = 0.f;
#pragma unroll
    for (int i = 0; i < 8; ++i) {
      float4 v = *(const float4*)(src + t * PCH + r * 32 + i * 4);
      s += v.x * v.x + v.y * v.y + v.z * v.z + v.w * v.w;
    }
    nrm[tid] = s;
  }
  __syncthreads();
  if (tid < 128) {
    int sec = tid >> 6, t = tid & 63;
    float s = nrm[sec * 256 + t * 4] + nrm[sec * 256 + t * 4 + 1] +
              nrm[sec * 256 + t * 4 + 2] + nrm[sec * 256 + t * 4 + 3];
    float inv = rsqrtf(s + 1e-6f);
    if (sec == 0) inv *= 0.08838834764831845f;  // q scale D^-0.5
    nrm[512 + tid] = inv;
  }
  __syncthreads();
  for (int it = 0; it < 8; ++it) {
    int f4 = tid + (it << 9);
    int sec = f4 >> 11, t = (f4 >> 5) & 63, d4 = f4 & 31;
    float* dst = (sec == 0) ? qL : kL;
    float inv = nrm[512 + sec * 64 + t];
    float4 v = *(float4*)(dst + t * PCH + d4 * 4);
    v.x *= inv; v.y *= inv; v.z *= inv; v.w *= inv;
    *(float4*)(dst + t * PCH + d4 * 4) = v;
  }
  __syncthreads();

  // (c) writeouts: q~ (tiled), kbar^T
  {
    int tW = tid >> 3, g = tid & 7;
    size_t qb = (size_t)bid * 8192 + g * 1024 + tW * 16;
    size_t kb = (size_t)bid * 8192;
#pragma unroll
    for (int i = 0; i < 4; ++i) {
      int d = g * 16 + 4 * i;
      float4 qv = *(const float4*)(qL + tW * PCH + d);
      float4 cg4 = *(const float4*)(cgL + tW * PCH + d);
      float4 o;
      o.x = qv.x * __expf(cg4.x); o.y = qv.y * __expf(cg4.y);
      o.z = qv.z * __expf(cg4.z); o.w = qv.w * __expf(cg4.w);
      *(float4*)(qt_g + qb + 4 * i) = o;
      float4 kv = *(const float4*)(kL + tW * PCH + d);
      float4 c63 = *(const float4*)(cgL + 63 * PCH + d);
      kbt_g[kb + (size_t)(d + 0) * 64 + tW] = kv.x * __expf(c63.x - cg4.x);
      kbt_g[kb + (size_t)(d + 1) * 64 + tW] = kv.y * __expf(c63.y - cg4.y);
      kbt_g[kb + (size_t)(d + 2) * 64 + tW] = kv.z * __expf(c63.z - cg4.z);
      kbt_g[kb + (size_t)(d + 3) * 64 + tW] = kv.w * __expf(c63.w - cg4.w);
    }
  }

  // (d) pair-work: A (strict lower, scaled by b -> M) and W (incl lower)
  // 4x4 tiles over (t,s), lower-triangular tile set, full-d per thread.
  if (tid < 136) {
    int L = tid;
    int tt = (int)((sqrtf(8.f * L + 1.f) - 1.f) * 0.5f);
    while ((tt + 1) * (tt + 2) / 2 <= L) ++tt;
    while (tt * (tt + 1) / 2 > L) --tt;
    int ss = L - tt * (tt + 1) / 2;
    int ta = tt * 4, sa = ss * 4;
    float accA[16], accW[16];
#pragma unroll
    for (int i = 0; i < 16; ++i) { accA[i] = 0.f; accW[i] = 0.f; }
    for (int d = 0; d < 128; d += 4) {
      float kt[4][4], qt4[4][4], ct[4][4], ks4[4][4], cs4[4][4];
#pragma unroll
      for (int i = 0; i < 4; ++i) {
        *(float4*)kt[i]  = *(const float4*)(kL + (ta + i) * PCH + d);
        *(float4*)qt4[i] = *(const float4*)(qL + (ta + i) * PCH + d);
        *(float4*)ct[i]  = *(const float4*)(cgL + (ta + i) * PCH + d);
        *(float4*)ks4[i] = *(const float4*)(kL + (sa + i) * PCH + d);
        *(float4*)cs4[i] = *(const float4*)(cgL + (sa + i) * PCH + d);
      }
#pragma unroll
      for (int i = 0; i < 4; ++i)
#pragma unroll
        for (int j = 0; j < 4; ++j)
#pragma unroll
          for (int dd = 0; dd < 4; ++dd) {
            float diff = ct[i][dd] - cs4[j][dd];
            float e = (diff < 0.f) ? __expf(diff) : __expf(fminf(diff, 0.f) ) * ((diff<=0.f)?1.f:1.f);
            // valid cells always have diff<=0 (+tiny fp noise); clamp for discarded cells
            e = __expf(fminf(diff, 0.f));
            float m = e * ks4[j][dd];
            accA[i * 4 + j] += kt[i][dd] * m;
            accW[i * 4 + j] += qt4[i][dd] * m;
          }
    }
    size_t wb = (size_t)bid * 4096;
#pragma unroll
    for (int i = 0; i < 4; ++i)
#pragma unroll
      for (int j = 0; j < 4; ++j) {
        int t = ta + i, s = sa + j;
        if (s < t) ML[t * MP + s] = bL[t] * accA[i * 4 + j];
        float wv = (s <= t) ? accW[i * 4 + j] : 0.f;
        w_g[wb + (size_t)(s >> 3) * 512 + t * 8 + (s & 7)] = wv;
      }
  }
  __syncthreads();

  // (e) N = (I + B A)^-1, stored transposed in NT
  for (int i = tid; i < 4352; i += 512) NT[i] = 0.f;
  __syncthreads();
  if (tid < 64) {
    int b4 = tid >> 4, j = tid & 15, bo = b4 * 16;
    NT[(bo + j) * MP + bo + j] = 1.f;
    for (int t = j + 1; t < 16; ++t) {
      float s = 0.f;
      for (int sx = j; sx < t; ++sx)
        s += ML[(bo + t) * MP + bo + sx] * NT[(bo + j) * MP + bo + sx];
      NT[(bo + j) * MP + bo + t] = -s;
    }
  }
  __syncthreads();
  for (int lev = 1; lev <= 3; ++lev) {
    int nb = 4 - lev;
    for (int idx = tid; idx < nb * 256; idx += 512) {
      int J = idx >> 8, I = J + lev;
      int i = (idx >> 4) & 15, j = idx & 15;
      float s = 0.f;
      for (int P = J; P < I; ++P)
#pragma unroll 4
        for (int p = 0; p < 16; ++p)
          s += ML[(16 * I + i) * MP + 16 * P + p] * NT[(16 * J + j) * MP + 16 * P + p];
      GB[J * 256 + i * 16 + j] = s;
    }
    __syncthreads();
    for (int idx = tid; idx < nb * 256; idx += 512) {
      int J = idx >> 8, I = J + lev;
      int i = (idx >> 4) & 15, j = idx & 15;
      float s = 0.f;
#pragma unroll 4
      for (int p = 0; p < 16; ++p)
        s += NT[(16 * I + p) * MP + 16 * I + i] * GB[J * 256 + p * 16 + j];
      NT[(16 * J + j) * MP + 16 * I + i] = -s;
    }
    __syncthreads();
  }

  // (f) RHS_z = b * k * e^cg ; Z = N * RHS_z  (tiled store)
  {
    int tW = tid >> 3, g = tid & 7;
    float b = bL[tW];
#pragma unroll
    for (int i = 0; i < 4; ++i) {
      int d = g * 16 + 4 * i;
      float4 kv = *(const float4*)(kL + tW * PCH + d);
      float4 cg4 = *(const float4*)(cgL + tW * PCH + d);
      float4 r;
      r.x = b * kv.x * __expf(cg4.x); r.y = b * kv.y * __expf(cg4.y);
      r.z = b * kv.z * __expf(cg4.z); r.w = b * kv.w * __expf(cg4.w);
      *(float4*)(qL + tW * PCH + d) = r;
    }
  }
  __syncthreads();
  {
    int t4 = tid >> 5, c4 = tid & 31;
    float acc[4][4];
#pragma unroll
    for (int i = 0; i < 4; ++i)
#pragma unroll
      for (int j = 0; j < 4; ++j) acc[i][j] = 0.f;
    for (int s = 0; s < 64; ++s) {
      float nv[4], rv[4];
      *(float4*)nv = *(const float4*)(NT + s * MP + t4 * 4);
      *(float4*)rv = *(const float4*)(qL + s * PCH + c4 * 4);
#pragma unroll
      for (int i = 0; i < 4; ++i)
#pragma unroll
        for (int j = 0; j < 4; ++j) acc[i][j] += nv[i] * rv[j];
    }
    size_t zb = (size_t)bid * 8192 + (size_t)(c4 >> 2) * 1024 + (c4 & 3) * 4;
#pragma unroll
    for (int i = 0; i < 4; ++i) {
      float4 o; o.x = acc[i][0]; o.y = acc[i][1]; o.z = acc[i][2]; o.w = acc[i][3];
      *(float4*)(z_g + zb + (size_t)(t4 * 4 + i) * 16) = o;
    }
  }
  __syncthreads();

  // (g) RHS_v = b * silu(conv(v)) ; U0 = N * RHS_v (natural store)
  for (int it = 0; it < 16; ++it) {
    int cell = tid + (it << 9);
    int d = cell & 127, t = cell >> 7;
    int ch = 2 * CH1 + h * HD + d;
    float4 w4 = ((const float4*)cw)[ch];
    int rbase = t0 + t - 3;
    float acc;
    if (rbase >= 0) {
      const float* mp = mixed + (size_t)rbase * CH3 + ch;
      acc = mp[0] * w4.x + mp[CH3] * w4.y + mp[2 * CH3] * w4.z + mp[3 * CH3] * w4.w;
    } else {
      acc = 0.f;
      if (rbase + 0 >= 0) acc += mixed[(size_t)(rbase + 0) * CH3 + ch] * w4.x;
      if (rbase + 1 >= 0) acc += mixed[(size_t)(rbase + 1) * CH3 + ch] * w4.y;
      if (rbase + 2 >= 0) acc += mixed[(size_t)(rbase + 2) * CH3 + ch] * w4.z;
      acc += mixed[(size_t)(rbase + 3) * CH3 + ch] * w4.w;
    }
    acc = acc / (1.f + __expf(-acc));
    qL[t * PCH + d] = bL[t] * acc;
  }
  __syncthreads();
  {
    int t4 = tid >> 5, c4 = tid & 31;
    float acc[4][4];
#pragma unroll
    for (int i = 0; i < 4; ++i)
#pragma unroll
      for (int j = 0; j < 4; ++j) acc[i][j] = 0.f;
    for (int s = 0; s < 64; ++s) {
      float nv[4], rv[4];
      *(float4*)nv = *(const float4*)(NT + s * MP + t4 * 4);
      *(float4*)rv = *(const float4*)(qL + s * PCH + c4 * 4);
#pragma unroll
      for (int i = 0; i < 4; ++i)
#pragma unroll
        for (int j = 0; j < 4; ++j) acc[i][j] += nv[i] * rv[j];
    }
#pragma unroll
    for (int i = 0; i < 4; ++i) {
      size_t ob = ((size_t)(t0 + t4 * 4 + i) * NH + h) * HD + c4 * 4;
      float4 o; o.x = acc[i][0]; o.y = acc[i][1]; o.z = acc[i][2]; o.w = acc[i][3];
      *(float4*)(u0_g + ob) = o;
    }
  }
}

// ---------------------------------------------------------------------------
// Kernel B: sequential over 128 chunks; parallel over (head, 8-col v-group).
// Per chunk: T=Z*S, U=U0-T, O=Q~*S + W*U, S = e*S + Kbar^T*U.
// ---------------------------------------------------------------------------
__global__ __launch_bounds__(512, 2)
void kda_scan3(const float* __restrict__ qt_g, const float* __restrict__ kbt_g,
               const float* __restrict__ u0_g, const float* __restrict__ z_g,
               const float* __restrict__ w_g, const float* __restrict__ ecg_g,
               float* __restrict__ out, float* __restrict__ slabs) {
  __shared__ float Tp[4224], Op[4224];   // [8g][8j][66]
  const int tid = threadIdx.x;
  const int bid = blockIdx.x;
  const int h = bid & 15, vg = bid >> 4;
  float* Sslab = slabs + (size_t)bid * 2048;  // [128][8]
  float* Un = Sslab + 1024;                   // [64][8]
  float* Ut = Un + 512;                       // [8][64]
  for (int i = tid; i < 1024; i += 512) Sslab[i] = 0.f;
  __threadfence_block();
  __syncthreads();
  const int gA = tid >> 6, tA = tid & 63;
  const int tB = tid >> 3, jB = tid & 7;
  const int kC = tid & 127, j2 = tid >> 7;
  for (int c = 0; c < NC; ++c) {
    const int ch = c * 16 + h;
    // P1: partial T = Z*S, O1 = Q~*S over this wave's 16-d slice
    const float* zb = z_g + (size_t)ch * 8192 + gA * 1024 + tA * 16;
    const float* qb = qt_g + (size_t)ch * 8192 + gA * 1024 + tA * 16;
    float z[16], q[16];
#pragma unroll
    for (int i = 0; i < 4; ++i) {
      *(float4*)(z + 4 * i) = *(const float4*)(zb + 4 * i);
      *(float4*)(q + 4 * i) = *(const float4*)(qb + 4 * i);
    }
    float Ta[8], Oa[8];
#pragma unroll
    for (int j = 0; j < 8; ++j) { Ta[j] = 0.f; Oa[j] = 0.f; }
    const float* Sg = Sslab + gA * 128;
#pragma unroll
    for (int dd = 0; dd < 16; ++dd) {
      float s8[8];
      *(float4*)s8 = *(const float4*)(Sg + dd * 8);
      *(float4*)(s8 + 4) = *(const float4*)(Sg + dd * 8 + 4);
      float zz = z[dd], qq = q[dd];
#pragma unroll
      for (int j = 0; j < 8; ++j) { Ta[j] += zz * s8[j]; Oa[j] += qq * s8[j]; }
    }
#pragma unroll
    for (int j = 0; j < 8; ++j) {
      Tp[gA * 528 + j * 66 + tA] = Ta[j];
      Op[gA * 528 + j * 66 + tA] = Oa[j];
    }
    __syncthreads();
    // P2: reduce partials, U = U0 - T (store both layouts), keep O1
    float Osave;
    {
      float Ts = 0.f, Os = 0.f;
#pragma unroll
      for (int g = 0; g < 8; ++g) {
        Ts += Tp[g * 528 + jB * 66 + tB];
        Os += Op[g * 528 + jB * 66 + tB];
      }
      float u0 = u0_g[((size_t)(c * 64 + tB) * NH + h) * HD + vg * 8 + jB];
      float U = u0 - Ts;
      Un[tB * 8 + jB] = U;
      Ut[jB * 64 + tB] = U;
      Osave = Os;
    }
    __threadfence_block();
    __syncthreads();
    // P3: partial W*U over this wave's 8-s slice (reuse Tp)
    {
      const float* wb = w_g + (size_t)ch * 4096 + gA * 512 + tA * 8;
      float w8[8];
      *(float4*)w8 = *(const float4*)(wb);
      *(float4*)(w8 + 4) = *(const float4*)(wb + 4);
      float Wa[8];
#pragma unroll
      for (int j = 0; j < 8; ++j) Wa[j] = 0.f;
#pragma unroll
      for (int sp = 0; sp < 8; ++sp) {
        const float* ur = Un + (gA * 8 + sp) * 8;
        float u8[8];
        *(float4*)u8 = *(const float4*)(ur);
        *(float4*)(u8 + 4) = *(const float4*)(ur + 4);
        float wv = w8[sp];
#pragma unroll
        for (int j = 0; j < 8; ++j) Wa[j] += wv * u8[j];
      }
#pragma unroll
      for (int j = 0; j < 8; ++j) Tp[gA * 528 + j * 66 + tA] = Wa[j];
    }
    __syncthreads();
    // P4: O = O1 + sum_g W-partials
    {
      float O2 = 0.f;
#pragma unroll
      for (int g = 0; g < 8; ++g) O2 += Tp[g * 528 + jB * 66 + tB];
      out[((size_t)(c * 64 + tB) * NH + h) * HD + vg * 8 + jB] = Osave + O2;
    }
    // P5: S = e^{cgC} * S + Kbar^T * U
    {
      float a0 = 0.f, a1 = 0.f;
      const float* kb = kbt_g + (size_t)ch * 8192 + (size_t)kC * 64;
      const float* u0r = Ut + (2 * j2) * 64;
      const float* u1r = Ut + (2 * j2 + 1) * 64;
#pragma unroll
      for (int t4 = 0; t4 < 16; ++t4) {
        float4 kv = *(const float4*)(kb + 4 * t4);
        float4 ua = *(const float4*)(u0r + 4 * t4);
        float4 ub = *(const float4*)(u1r + 4 * t4);
        a0 += kv.x * ua.x + kv.y * ua.y + kv.z * ua.z + kv.w * ua.w;
        a1 += kv.x * ub.x + kv.y * ub.y + kv.z * ub.z + kv.w * ub.w;
      }
      float e = ecg_g[(size_t)ch * 128 + kC];
      float* sp2 = Sslab + kC * 8 + 2 * j2;
      float s0 = sp2[0], s1 = sp2[1];
      sp2[0] = e * s0 + a0;
      sp2[1] = e * s1 + a1;
    }
    __threadfence_block();
    __syncthreads();
  }
}

// ---------------------------------------------------------------------------
extern "C" void kernel_launch(void* const* d_in, const int* in_sizes, int n_in,
                              void* d_out, int out_size, void* d_ws, size_t ws_size,
                              hipStream_t stream) {
  const float* mixed = (const float*)d_in[0];
  const float* fg    = (const float*)d_in[1];
  const float* beta  = (const float*)d_in[2];
  const float* cw    = (const float*)d_in[3];
  const float* dtb   = (const float*)d_in[4];
  const float* alog  = (const float*)d_in[5];
  float* ws = (float*)d_ws;
  float* qt_g  = ws + QT_OFF;
  float* kbt_g = ws + KBT_OFF;
  float* u0_g  = ws + U0_OFF;
  float* z_g   = ws + Z_OFF;
  float* w_g   = ws + W_OFF;
  float* ecg_g = ws + ECG_OFF;
  float* slabs = ws + SLAB_OFF;

  hipLaunchKernelGGL(kda_chunk, dim3(NC * NH), dim3(512), 0, stream,
                     mixed, fg, beta, cw, dtb, alog,
                     qt_g, kbt_g, u0_g, z_g, w_g, ecg_g);
  hipLaunchKernelGGL(kda_scan3, dim3(256), dim3(512), 0, stream,
                     qt_g, kbt_g, u0_g, z_g, w_g, ecg_g, (float*)d_out, slabs);
  (void)in_sizes; (void)n_in; (void)out_size; (void)ws_size;
}